// Round 3
// baseline (627.732 us; speedup 1.0000x reference)
//
#include <hip/hip_runtime.h>

// Problem constants
#define C_DIM   256
#define K_CODES 1024
#define HW      1024
#define NPOS    32768            // B*H*W
#define ZQ_ELEMS 8388608         // B*C*H*W

typedef float  f32x4  __attribute__((ext_vector_type(4)));
typedef __bf16 bf16x8 __attribute__((ext_vector_type(8)));

struct Cand { float s0, s1; int i0, i1; };

// workspace byte offsets
#define OFF_EF    0                      // 1024 f32
#define OFF_BB    4096                   // 512 KB swizzled bf16 codebook image
#define OFF_IDX   (4096 + 524288)        // 32768 int
#define OFF_LIST  (OFF_IDX + 131072)     // 32768 int
#define OFF_COUNT (OFF_LIST + 131072)    // int
#define OFF_LSUM  (OFF_COUNT + 8)        // double

#define TAU 6e-4f   // bf16-split scoring error is ~6e-5 rms per score; 6e-4 = safe flag margin

// ---------------------------------------------------------------------------
// k1: faithful fp32 ||e_k||^2 (numpy pairwise emulation, validated round 2)
//     + pack codebook to swizzled bf16 block image Bb + init count/lsum.
// Bb layout: blocks of 8KB = [tile=k>>7 (8)][step=0..7][r=k&127][32 k-elems],
// row = 64B, byte-in-row = (j*2) ^ (((r^(r>>2))&3)<<4)   (bank swizzle)
// ---------------------------------------------------------------------------
__global__ __launch_bounds__(256) void k1_prep(const float* __restrict__ emb,
                                               float* __restrict__ Ef,
                                               char* __restrict__ Bb,
                                               int* __restrict__ count,
                                               double* __restrict__ lsum) {
    const int k = blockIdx.x * 256 + threadIdx.x;
    if (k == 0) { *count = 0; *lsum = 0.0; }
    const float* a = emb + (size_t)k * C_DIM;

    float blk[2];
#pragma unroll
    for (int h = 0; h < 2; ++h) {
        const float* p = a + h * 128;
        float4 v0 = *reinterpret_cast<const float4*>(p);
        float4 v1 = *reinterpret_cast<const float4*>(p + 4);
        float r[8];
        r[0] = __fmul_rn(v0.x, v0.x); r[1] = __fmul_rn(v0.y, v0.y);
        r[2] = __fmul_rn(v0.z, v0.z); r[3] = __fmul_rn(v0.w, v0.w);
        r[4] = __fmul_rn(v1.x, v1.x); r[5] = __fmul_rn(v1.y, v1.y);
        r[6] = __fmul_rn(v1.z, v1.z); r[7] = __fmul_rn(v1.w, v1.w);
        for (int i = 8; i < 128; i += 8) {
            float4 w0 = *reinterpret_cast<const float4*>(p + i);
            float4 w1 = *reinterpret_cast<const float4*>(p + i + 4);
            r[0] = __fadd_rn(r[0], __fmul_rn(w0.x, w0.x));
            r[1] = __fadd_rn(r[1], __fmul_rn(w0.y, w0.y));
            r[2] = __fadd_rn(r[2], __fmul_rn(w0.z, w0.z));
            r[3] = __fadd_rn(r[3], __fmul_rn(w0.w, w0.w));
            r[4] = __fadd_rn(r[4], __fmul_rn(w1.x, w1.x));
            r[5] = __fadd_rn(r[5], __fmul_rn(w1.y, w1.y));
            r[6] = __fadd_rn(r[6], __fmul_rn(w1.z, w1.z));
            r[7] = __fadd_rn(r[7], __fmul_rn(w1.w, w1.w));
        }
        blk[h] = __fadd_rn(__fadd_rn(__fadd_rn(r[0], r[1]), __fadd_rn(r[2], r[3])),
                           __fadd_rn(__fadd_rn(r[4], r[5]), __fadd_rn(r[6], r[7])));
    }
    Ef[k] = __fadd_rn(blk[0], blk[1]);

    // --- pack Bb ---
    const int r = k & 127, tile = k >> 7;
    const int xr = ((r ^ (r >> 2)) & 3) << 4;
    char* rowbase = Bb + (size_t)(tile * 8) * 8192 + r * 64;
#pragma unroll
    for (int s = 0; s < 8; ++s) {
        const float* ep = a + s * 32;
        char* sb = rowbase + s * 8192;
#pragma unroll
        for (int g = 0; g < 4; ++g) {
            union { __bf16 h[8]; uint4 v; } pk;
#pragma unroll
            for (int j = 0; j < 8; ++j) pk.h[j] = (__bf16)ep[g * 8 + j];
            *reinterpret_cast<uint4*>(sb + ((g * 16) ^ xr)) = pk.v;
        }
    }
}

// ---------------------------------------------------------------------------
// k2: MFMA scoring GEMM. Per block: 128 positions x all 1024 codes, Keff=512
// (z_hi||z_lo vs e_hi||e_hi). A (z) transposed+split into LDS once
// (128 rows x 512 k bf16, row=1024B, byte k*2 XOR ((row^(row>>2))&7)<<4).
// B streamed from Bb, double-buffered 8KB, 1 barrier per 32-k step.
// Epilogue: per-row top-2 + flag + idxf, fully fused.
// ---------------------------------------------------------------------------
__global__ __launch_bounds__(512, 2) void k2_gemm(const float* __restrict__ z,
                                                  const char* __restrict__ Bb,
                                                  const float* __restrict__ Ef,
                                                  int* __restrict__ idxf,
                                                  int* __restrict__ list,
                                                  int* __restrict__ count) {
    __shared__ char smem[147456];          // 128KB A + 2x8KB B (Cand reuses A)
    char* As = smem;
    char* Bs = smem + 131072;

    const int t    = threadIdx.x;
    const int bidx = blockIdx.x;
    const int lane = t & 63;
    const int l15  = lane & 15, kg = lane >> 4;
    const int wid  = t >> 6;
    const int wM   = wid >> 1, wN = wid & 1;   // 4 x 2 wave grid, wave tile 32M x 64N

    // ---- A fill: transpose z[b][c][hw] tile -> A[hw][k] bf16 hi|lo ----
    const float* zt = z + (size_t)(bidx >> 3) * (C_DIM * HW) + (bidx & 7) * 128;
#pragma unroll
    for (int p = 0; p < 8; ++p) {
        const int pi  = p * 512 + t;
        const int c2  = pi >> 5;         // c-pair 0..127
        const int hwg = pi & 31;
        const float* p0 = zt + (size_t)(2 * c2) * HW + hwg * 4;
        const float4 f0 = *reinterpret_cast<const float4*>(p0);
        const float4 f1 = *reinterpret_cast<const float4*>(p0 + HW);
        const float a0v[4] = {f0.x, f0.y, f0.z, f0.w};
        const float a1v[4] = {f1.x, f1.y, f1.z, f1.w};
#pragma unroll
        for (int i = 0; i < 4; ++i) {
            const int hw = hwg * 4 + i;
            const int xr = ((hw ^ (hw >> 2)) & 7) << 4;
            const int koff = (c2 * 4) ^ xr;
            char* rowp = As + hw * 1024;
            const float x0 = a0v[i], x1 = a1v[i];
            const __bf16 h0 = (__bf16)x0, h1 = (__bf16)x1;
            const __bf16 l0 = (__bf16)(x0 - (float)h0);
            const __bf16 l1 = (__bf16)(x1 - (float)h1);
            union { __bf16 h[2]; unsigned int u; } ph, pl;
            ph.h[0] = h0; ph.h[1] = h1;
            pl.h[0] = l0; pl.h[1] = l1;
            *reinterpret_cast<unsigned int*>(rowp + koff) = ph.u;
            *reinterpret_cast<unsigned int*>(rowp + 512 + koff) = pl.u;
        }
    }
    __syncthreads();

    // per-lane fragment addressing
    int arow[2], axr[2];
#pragma unroll
    for (int mi = 0; mi < 2; ++mi) {
        arow[mi] = wM * 32 + mi * 16 + l15;
        axr[mi]  = ((arow[mi] ^ (arow[mi] >> 2)) & 7) << 4;
    }
    int bcl[4], bxr[4];
#pragma unroll
    for (int ni = 0; ni < 4; ++ni) {
        bcl[ni] = wN * 64 + ni * 16 + l15;
        bxr[ni] = ((bcl[ni] ^ (bcl[ni] >> 2)) & 3) << 4;
    }

    float bs0[8], bs1[8];
    int   bi0[8], bi1[8];
#pragma unroll
    for (int s = 0; s < 8; ++s) { bs0[s] = 1e30f; bs1[s] = 1e30f; bi0[s] = 1 << 29; bi1[s] = 1 << 29; }

    const uint4* BbU = reinterpret_cast<const uint4*>(Bb);

    for (int nt = 0; nt < 8; ++nt) {
        f32x4 acc[2][4];
#pragma unroll
        for (int mi = 0; mi < 2; ++mi)
#pragma unroll
        for (int ni = 0; ni < 4; ++ni) acc[mi][ni] = f32x4{0.f, 0.f, 0.f, 0.f};

        // prologue: stage step 0 into buf0
        {
            uint4 v = BbU[(size_t)(nt * 8) * 512 + t];
            *reinterpret_cast<uint4*>(Bs + t * 16) = v;
        }
        __syncthreads();

        for (int g = 0; g < 16; ++g) {
            uint4 vn;
            if (g < 15) vn = BbU[(size_t)(nt * 8 + ((g + 1) & 7)) * 512 + t];  // issue early

            const char* bbuf = Bs + (g & 1) * 8192;
            bf16x8 af[2];
#pragma unroll
            for (int mi = 0; mi < 2; ++mi)
                af[mi] = *reinterpret_cast<const bf16x8*>(
                    As + arow[mi] * 1024 + ((g * 64 + kg * 16) ^ axr[mi]));
            bf16x8 bfv[4];
#pragma unroll
            for (int ni = 0; ni < 4; ++ni)
                bfv[ni] = *reinterpret_cast<const bf16x8*>(
                    bbuf + bcl[ni] * 64 + ((kg * 16) ^ bxr[ni]));
#pragma unroll
            for (int mi = 0; mi < 2; ++mi)
#pragma unroll
            for (int ni = 0; ni < 4; ++ni)
                acc[mi][ni] = __builtin_amdgcn_mfma_f32_16x16x32_bf16(af[mi], bfv[ni], acc[mi][ni], 0, 0, 0);

            if (g < 15)
                *reinterpret_cast<uint4*>(Bs + ((g + 1) & 1) * 8192 + t * 16) = vn;  // write late
            __syncthreads();
        }

        // epilogue: fold scores into per-lane top-2 (codes ascending per slot)
#pragma unroll
        for (int ni = 0; ni < 4; ++ni) {
            const int code = nt * 128 + bcl[ni];
            const float ef = Ef[code];
#pragma unroll
            for (int mi = 0; mi < 2; ++mi) {
#pragma unroll
                for (int rr = 0; rr < 4; ++rr) {
                    const float s = ef - 2.0f * acc[mi][ni][rr];
                    const int slot = mi * 4 + rr;
                    if (s < bs0[slot] || (s == bs0[slot] && code < bi0[slot])) {
                        bs1[slot] = bs0[slot]; bi1[slot] = bi0[slot];
                        bs0[slot] = s; bi0[slot] = code;
                    } else if (s < bs1[slot] || (s == bs1[slot] && code < bi1[slot])) {
                        bs1[slot] = s; bi1[slot] = code;
                    }
                }
            }
        }
    }

    // cross-lane top-2 merge over the 16 column-lanes
#pragma unroll
    for (int slot = 0; slot < 8; ++slot) {
        float s0 = bs0[slot], s1 = bs1[slot];
        int   i0 = bi0[slot], i1 = bi1[slot];
#pragma unroll
        for (int m = 1; m <= 8; m <<= 1) {
            const float os0 = __shfl_xor(s0, m), os1 = __shfl_xor(s1, m);
            const int   oi0 = __shfl_xor(i0, m), oi1 = __shfl_xor(i1, m);
            if (os0 < s0 || (os0 == s0 && oi0 < i0)) {
                s1 = s0; i1 = i0; s0 = os0; i0 = oi0;
                if (os1 < s1 || (os1 == s1 && oi1 < i1)) { s1 = os1; i1 = oi1; }
            } else if (os0 < s1 || (os0 == s1 && oi0 < i1)) { s1 = os0; i1 = oi0; }
        }
        bs0[slot] = s0; bs1[slot] = s1; bi0[slot] = i0; bi1[slot] = i1;
    }

    // A-region is dead now; reuse as Cand[128][2]
    Cand* cl = reinterpret_cast<Cand*>(smem);
    if (l15 == 0) {
#pragma unroll
        for (int slot = 0; slot < 8; ++slot) {
            const int mi = slot >> 2, rr = slot & 3;
            const int row = wM * 32 + mi * 16 + kg * 4 + rr;
            Cand c; c.s0 = bs0[slot]; c.s1 = bs1[slot]; c.i0 = bi0[slot]; c.i1 = bi1[slot];
            cl[row * 2 + wN] = c;
        }
    }
    __syncthreads();

    if (t < 128) {
        Cand a = cl[t * 2];
        const Cand b = cl[t * 2 + 1];
        if (b.s0 < a.s0 || (b.s0 == a.s0 && b.i0 < a.i0)) {
            const float ts = a.s0; const int ti = a.i0;
            a.s0 = b.s0; a.i0 = b.i0;
            a.s1 = ts;   a.i1 = ti;
            if (b.s1 < a.s1 || (b.s1 == a.s1 && b.i1 < a.i1)) { a.s1 = b.s1; a.i1 = b.i1; }
        } else if (b.s0 < a.s1 || (b.s0 == a.s1 && b.i0 < a.i1)) { a.s1 = b.s0; a.i1 = b.i0; }
        const int n = bidx * 128 + t;
        idxf[n] = a.i0;
        if (a.s1 - a.s0 < TAU) {
            const int p = atomicAdd(count, 1);
            list[p] = n;
        }
    }
}

// ---------------------------------------------------------------------------
// k3: faithful fp32 re-score of flagged rows (numpy-semantics; validated r2)
// ---------------------------------------------------------------------------
__global__ __launch_bounds__(256) void k3_refine(const float* __restrict__ z,
                                                 const float* __restrict__ emb,
                                                 const float* __restrict__ Ef,
                                                 const int* __restrict__ list,
                                                 const int* __restrict__ count,
                                                 int* __restrict__ idxf) {
    __shared__ float zsh[C_DIM];
    __shared__ float sZn;
    __shared__ float rd[256];
    __shared__ int   ri[256];
    const int t = threadIdx.x;
    const int cnt = *count;
    for (int li = blockIdx.x; li < cnt; li += gridDim.x) {
        const int r = list[li];
        const int b = r >> 10, hw = r & 1023;
        zsh[t] = z[((size_t)b * C_DIM + t) * HW + hw];
        __syncthreads();
        if (t == 0) {
            float blk[2];
#pragma unroll
            for (int h = 0; h < 2; ++h) {
                const float* p = zsh + h * 128;
                float rr[8];
#pragma unroll
                for (int j = 0; j < 8; ++j) rr[j] = __fmul_rn(p[j], p[j]);
                for (int i = 8; i < 128; i += 8) {
#pragma unroll
                    for (int j = 0; j < 8; ++j)
                        rr[j] = __fadd_rn(rr[j], __fmul_rn(p[i + j], p[i + j]));
                }
                blk[h] = __fadd_rn(__fadd_rn(__fadd_rn(rr[0], rr[1]), __fadd_rn(rr[2], rr[3])),
                                   __fadd_rn(__fadd_rn(rr[4], rr[5]), __fadd_rn(rr[6], rr[7])));
            }
            sZn = __fadd_rn(blk[0], blk[1]);
        }
        __syncthreads();
        const float zn = sZn;
        float bd = 1e30f; int bidx2 = 1 << 29;
#pragma unroll
        for (int q = 0; q < 4; ++q) {
            const int code = t * 4 + q;
            const float* e = emb + (size_t)code * C_DIM;
            float acc = 0.f;
            for (int c = 0; c < C_DIM; c += 4) {
                const float4 ev = *reinterpret_cast<const float4*>(e + c);
                acc = __fmaf_rn(zsh[c + 0], ev.x, acc);
                acc = __fmaf_rn(zsh[c + 1], ev.y, acc);
                acc = __fmaf_rn(zsh[c + 2], ev.z, acc);
                acc = __fmaf_rn(zsh[c + 3], ev.w, acc);
            }
            const float dk = __fsub_rn(__fadd_rn(zn, Ef[code]), __fmul_rn(2.0f, acc));
            if (dk < bd) { bd = dk; bidx2 = code; }
        }
        rd[t] = bd; ri[t] = bidx2;
        __syncthreads();
        for (int st = 128; st > 0; st >>= 1) {
            if (t < st) {
                if (rd[t + st] < rd[t] || (rd[t + st] == rd[t] && ri[t + st] < ri[t])) {
                    rd[t] = rd[t + st]; ri[t] = ri[t + st];
                }
            }
            __syncthreads();
        }
        if (t == 0) idxf[r] = ri[0];
        __syncthreads();
    }
}

// ---------------------------------------------------------------------------
// k4: zq straight-through + fp64 loss partial + indices-as-float
// ---------------------------------------------------------------------------
__global__ __launch_bounds__(256) void k4_out(const float* __restrict__ z,
                                              const float* __restrict__ emb,
                                              const int* __restrict__ idxf,
                                              float* __restrict__ out,
                                              double* __restrict__ lsum) {
    const int gid = blockIdx.x * 256 + threadIdx.x;
    if (gid < NPOS) out[(size_t)ZQ_ELEMS + 3 + gid] = (float)idxf[gid];

    const size_t stride = (size_t)gridDim.x * 256;
    double acc = 0.0;
    for (size_t v = (size_t)gid; v < (ZQ_ELEMS / 4); v += stride) {
        const size_t e = v * 4;
        const int hw = (int)(e & 1023);
        const int bc = (int)(e >> 10);
        const int c  = bc & 255;
        const int b  = bc >> 8;
        const int n  = b * 1024 + hw;
        const float4 zv = *reinterpret_cast<const float4*>(z + e);
        const int j0 = idxf[n], j1 = idxf[n + 1], j2 = idxf[n + 2], j3 = idxf[n + 3];
        const float e0 = emb[(size_t)j0 * C_DIM + c];
        const float e1 = emb[(size_t)j1 * C_DIM + c];
        const float e2 = emb[(size_t)j2 * C_DIM + c];
        const float e3 = emb[(size_t)j3 * C_DIM + c];
        float4 o;
        o.x = zv.x + (e0 - zv.x);
        o.y = zv.y + (e1 - zv.y);
        o.z = zv.z + (e2 - zv.z);
        o.w = zv.w + (e3 - zv.w);
        *reinterpret_cast<float4*>(out + e) = o;
        const double d0 = (double)e0 - (double)zv.x;
        const double d1 = (double)e1 - (double)zv.y;
        const double d2 = (double)e2 - (double)zv.z;
        const double d3 = (double)e3 - (double)zv.w;
        acc += d0 * d0 + d1 * d1 + d2 * d2 + d3 * d3;
    }
#pragma unroll
    for (int off = 32; off > 0; off >>= 1) acc += __shfl_down(acc, off);
    __shared__ double wsum[4];
    const int w = threadIdx.x >> 6, lanei = threadIdx.x & 63;
    if (lanei == 0) wsum[w] = acc;
    __syncthreads();
    if (threadIdx.x == 0) atomicAdd(lsum, wsum[0] + wsum[1] + wsum[2] + wsum[3]);
}

__global__ void k5_loss(const double* __restrict__ lsum, float* __restrict__ out) {
    const double m = *lsum / (double)ZQ_ELEMS;
    const float cm = (float)(0.25 * m);
    const float cb = (float)m;
    out[ZQ_ELEMS]     = cm + cb;
    out[ZQ_ELEMS + 1] = cm;
    out[ZQ_ELEMS + 2] = cb;
}

extern "C" void kernel_launch(void* const* d_in, const int* in_sizes, int n_in,
                              void* d_out, int out_size, void* d_ws, size_t ws_size,
                              hipStream_t stream) {
    const float* z   = (const float*)d_in[0];
    const float* emb = (const float*)d_in[1];
    float* out = (float*)d_out;
    char* ws = (char*)d_ws;

    float*  Ef    = (float*)(ws + OFF_EF);
    char*   Bb    = ws + OFF_BB;
    int*    idxf  = (int*)(ws + OFF_IDX);
    int*    list  = (int*)(ws + OFF_LIST);
    int*    count = (int*)(ws + OFF_COUNT);
    double* lsum  = (double*)(ws + OFF_LSUM);

    k1_prep<<<4, 256, 0, stream>>>(emb, Ef, Bb, count, lsum);
    k2_gemm<<<256, 512, 0, stream>>>(z, Bb, Ef, idxf, list, count);
    k3_refine<<<256, 256, 0, stream>>>(z, emb, Ef, list, count, idxf);
    k4_out<<<2048, 256, 0, stream>>>(z, emb, idxf, out, lsum);
    k5_loss<<<1, 1, 0, stream>>>(lsum, out);
}

// Round 4
// 321.792 us; speedup vs baseline: 1.9507x; 1.9507x over previous
//
#include <hip/hip_runtime.h>

// Problem constants
#define C_DIM   256
#define K_CODES 1024
#define HW      1024
#define NPOS    32768            // B*H*W
#define ZQ_ELEMS 8388608         // B*C*H*W

typedef float  f32x4  __attribute__((ext_vector_type(4)));
typedef __bf16 bf16x8 __attribute__((ext_vector_type(8)));

struct Cand { float s0, s1; int i0, i1; };

// workspace byte offsets
#define OFF_EF    0                      // 1024 f32
#define OFF_BB    4096                   // 512 KB swizzled bf16 codebook image
#define OFF_IDX   (4096 + 524288)        // 32768 int
#define OFF_LIST  (OFF_IDX + 131072)     // 32768 int
#define OFF_COUNT (OFF_LIST + 131072)    // int
#define OFF_LSUM  (OFF_COUNT + 8)        // double

#define TAU 6e-4f   // bf16-split scoring error ~4e-5 rms per score; 6e-4 = safe flag margin

// ---------------------------------------------------------------------------
// k1: faithful fp32 ||e_k||^2 (numpy pairwise emulation, validated round 2)
//     + pack codebook to swizzled bf16 block image Bb + init count/lsum.
// ---------------------------------------------------------------------------
__global__ __launch_bounds__(256) void k1_prep(const float* __restrict__ emb,
                                               float* __restrict__ Ef,
                                               char* __restrict__ Bb,
                                               int* __restrict__ count,
                                               double* __restrict__ lsum) {
    const int k = blockIdx.x * 256 + threadIdx.x;
    if (k == 0) { *count = 0; *lsum = 0.0; }
    const float* a = emb + (size_t)k * C_DIM;

    float blk[2];
#pragma unroll
    for (int h = 0; h < 2; ++h) {
        const float* p = a + h * 128;
        float4 v0 = *reinterpret_cast<const float4*>(p);
        float4 v1 = *reinterpret_cast<const float4*>(p + 4);
        float r[8];
        r[0] = __fmul_rn(v0.x, v0.x); r[1] = __fmul_rn(v0.y, v0.y);
        r[2] = __fmul_rn(v0.z, v0.z); r[3] = __fmul_rn(v0.w, v0.w);
        r[4] = __fmul_rn(v1.x, v1.x); r[5] = __fmul_rn(v1.y, v1.y);
        r[6] = __fmul_rn(v1.z, v1.z); r[7] = __fmul_rn(v1.w, v1.w);
        for (int i = 8; i < 128; i += 8) {
            float4 w0 = *reinterpret_cast<const float4*>(p + i);
            float4 w1 = *reinterpret_cast<const float4*>(p + i + 4);
            r[0] = __fadd_rn(r[0], __fmul_rn(w0.x, w0.x));
            r[1] = __fadd_rn(r[1], __fmul_rn(w0.y, w0.y));
            r[2] = __fadd_rn(r[2], __fmul_rn(w0.z, w0.z));
            r[3] = __fadd_rn(r[3], __fmul_rn(w0.w, w0.w));
            r[4] = __fadd_rn(r[4], __fmul_rn(w1.x, w1.x));
            r[5] = __fadd_rn(r[5], __fmul_rn(w1.y, w1.y));
            r[6] = __fadd_rn(r[6], __fmul_rn(w1.z, w1.z));
            r[7] = __fadd_rn(r[7], __fmul_rn(w1.w, w1.w));
        }
        blk[h] = __fadd_rn(__fadd_rn(__fadd_rn(r[0], r[1]), __fadd_rn(r[2], r[3])),
                           __fadd_rn(__fadd_rn(r[4], r[5]), __fadd_rn(r[6], r[7])));
    }
    Ef[k] = __fadd_rn(blk[0], blk[1]);

    // --- pack Bb ---
    const int r = k & 127, tile = k >> 7;
    const int xr = ((r ^ (r >> 2)) & 3) << 4;
    char* rowbase = Bb + (size_t)(tile * 8) * 8192 + r * 64;
#pragma unroll
    for (int s = 0; s < 8; ++s) {
        const float* ep = a + s * 32;
        char* sb = rowbase + s * 8192;
#pragma unroll
        for (int g = 0; g < 4; ++g) {
            union { __bf16 h[8]; uint4 v; } pk;
#pragma unroll
            for (int j = 0; j < 8; ++j) pk.h[j] = (__bf16)ep[g * 8 + j];
            *reinterpret_cast<uint4*>(sb + ((g * 16) ^ xr)) = pk.v;
        }
    }
}

// ---------------------------------------------------------------------------
// k2: MFMA scoring GEMM (validated round 3, unchanged).
// ---------------------------------------------------------------------------
__global__ __launch_bounds__(512, 2) void k2_gemm(const float* __restrict__ z,
                                                  const char* __restrict__ Bb,
                                                  const float* __restrict__ Ef,
                                                  int* __restrict__ idxf,
                                                  int* __restrict__ list,
                                                  int* __restrict__ count) {
    __shared__ char smem[147456];          // 128KB A + 2x8KB B (Cand reuses A)
    char* As = smem;
    char* Bs = smem + 131072;

    const int t    = threadIdx.x;
    const int bidx = blockIdx.x;
    const int lane = t & 63;
    const int l15  = lane & 15, kg = lane >> 4;
    const int wid  = t >> 6;
    const int wM   = wid >> 1, wN = wid & 1;   // 4 x 2 wave grid, wave tile 32M x 64N

    const float* zt = z + (size_t)(bidx >> 3) * (C_DIM * HW) + (bidx & 7) * 128;
#pragma unroll
    for (int p = 0; p < 8; ++p) {
        const int pi  = p * 512 + t;
        const int c2  = pi >> 5;         // c-pair 0..127
        const int hwg = pi & 31;
        const float* p0 = zt + (size_t)(2 * c2) * HW + hwg * 4;
        const float4 f0 = *reinterpret_cast<const float4*>(p0);
        const float4 f1 = *reinterpret_cast<const float4*>(p0 + HW);
        const float a0v[4] = {f0.x, f0.y, f0.z, f0.w};
        const float a1v[4] = {f1.x, f1.y, f1.z, f1.w};
#pragma unroll
        for (int i = 0; i < 4; ++i) {
            const int hw = hwg * 4 + i;
            const int xr = ((hw ^ (hw >> 2)) & 7) << 4;
            const int koff = (c2 * 4) ^ xr;
            char* rowp = As + hw * 1024;
            const float x0 = a0v[i], x1 = a1v[i];
            const __bf16 h0 = (__bf16)x0, h1 = (__bf16)x1;
            const __bf16 l0 = (__bf16)(x0 - (float)h0);
            const __bf16 l1 = (__bf16)(x1 - (float)h1);
            union { __bf16 h[2]; unsigned int u; } ph, pl;
            ph.h[0] = h0; ph.h[1] = h1;
            pl.h[0] = l0; pl.h[1] = l1;
            *reinterpret_cast<unsigned int*>(rowp + koff) = ph.u;
            *reinterpret_cast<unsigned int*>(rowp + 512 + koff) = pl.u;
        }
    }
    __syncthreads();

    int arow[2], axr[2];
#pragma unroll
    for (int mi = 0; mi < 2; ++mi) {
        arow[mi] = wM * 32 + mi * 16 + l15;
        axr[mi]  = ((arow[mi] ^ (arow[mi] >> 2)) & 7) << 4;
    }
    int bcl[4], bxr[4];
#pragma unroll
    for (int ni = 0; ni < 4; ++ni) {
        bcl[ni] = wN * 64 + ni * 16 + l15;
        bxr[ni] = ((bcl[ni] ^ (bcl[ni] >> 2)) & 3) << 4;
    }

    float bs0[8], bs1[8];
    int   bi0[8], bi1[8];
#pragma unroll
    for (int s = 0; s < 8; ++s) { bs0[s] = 1e30f; bs1[s] = 1e30f; bi0[s] = 1 << 29; bi1[s] = 1 << 29; }

    const uint4* BbU = reinterpret_cast<const uint4*>(Bb);

    for (int nt = 0; nt < 8; ++nt) {
        f32x4 acc[2][4];
#pragma unroll
        for (int mi = 0; mi < 2; ++mi)
#pragma unroll
        for (int ni = 0; ni < 4; ++ni) acc[mi][ni] = f32x4{0.f, 0.f, 0.f, 0.f};

        {
            uint4 v = BbU[(size_t)(nt * 8) * 512 + t];
            *reinterpret_cast<uint4*>(Bs + t * 16) = v;
        }
        __syncthreads();

        for (int g = 0; g < 16; ++g) {
            uint4 vn;
            if (g < 15) vn = BbU[(size_t)(nt * 8 + ((g + 1) & 7)) * 512 + t];

            const char* bbuf = Bs + (g & 1) * 8192;
            bf16x8 af[2];
#pragma unroll
            for (int mi = 0; mi < 2; ++mi)
                af[mi] = *reinterpret_cast<const bf16x8*>(
                    As + arow[mi] * 1024 + ((g * 64 + kg * 16) ^ axr[mi]));
            bf16x8 bfv[4];
#pragma unroll
            for (int ni = 0; ni < 4; ++ni)
                bfv[ni] = *reinterpret_cast<const bf16x8*>(
                    bbuf + bcl[ni] * 64 + ((kg * 16) ^ bxr[ni]));
#pragma unroll
            for (int mi = 0; mi < 2; ++mi)
#pragma unroll
            for (int ni = 0; ni < 4; ++ni)
                acc[mi][ni] = __builtin_amdgcn_mfma_f32_16x16x32_bf16(af[mi], bfv[ni], acc[mi][ni], 0, 0, 0);

            if (g < 15)
                *reinterpret_cast<uint4*>(Bs + ((g + 1) & 1) * 8192 + t * 16) = vn;
            __syncthreads();
        }

#pragma unroll
        for (int ni = 0; ni < 4; ++ni) {
            const int code = nt * 128 + bcl[ni];
            const float ef = Ef[code];
#pragma unroll
            for (int mi = 0; mi < 2; ++mi) {
#pragma unroll
                for (int rr = 0; rr < 4; ++rr) {
                    const float s = ef - 2.0f * acc[mi][ni][rr];
                    const int slot = mi * 4 + rr;
                    if (s < bs0[slot] || (s == bs0[slot] && code < bi0[slot])) {
                        bs1[slot] = bs0[slot]; bi1[slot] = bi0[slot];
                        bs0[slot] = s; bi0[slot] = code;
                    } else if (s < bs1[slot] || (s == bs1[slot] && code < bi1[slot])) {
                        bs1[slot] = s; bi1[slot] = code;
                    }
                }
            }
        }
    }

#pragma unroll
    for (int slot = 0; slot < 8; ++slot) {
        float s0 = bs0[slot], s1 = bs1[slot];
        int   i0 = bi0[slot], i1 = bi1[slot];
#pragma unroll
        for (int m = 1; m <= 8; m <<= 1) {
            const float os0 = __shfl_xor(s0, m), os1 = __shfl_xor(s1, m);
            const int   oi0 = __shfl_xor(i0, m), oi1 = __shfl_xor(i1, m);
            if (os0 < s0 || (os0 == s0 && oi0 < i0)) {
                s1 = s0; i1 = i0; s0 = os0; i0 = oi0;
                if (os1 < s1 || (os1 == s1 && oi1 < i1)) { s1 = os1; i1 = oi1; }
            } else if (os0 < s1 || (os0 == s1 && oi0 < i1)) { s1 = os0; i1 = oi0; }
        }
        bs0[slot] = s0; bs1[slot] = s1; bi0[slot] = i0; bi1[slot] = i1;
    }

    Cand* cl = reinterpret_cast<Cand*>(smem);
    if (l15 == 0) {
#pragma unroll
        for (int slot = 0; slot < 8; ++slot) {
            const int mi = slot >> 2, rr = slot & 3;
            const int row = wM * 32 + mi * 16 + kg * 4 + rr;
            Cand c; c.s0 = bs0[slot]; c.s1 = bs1[slot]; c.i0 = bi0[slot]; c.i1 = bi1[slot];
            cl[row * 2 + wN] = c;
        }
    }
    __syncthreads();

    if (t < 128) {
        Cand a = cl[t * 2];
        const Cand b = cl[t * 2 + 1];
        if (b.s0 < a.s0 || (b.s0 == a.s0 && b.i0 < a.i0)) {
            const float ts = a.s0; const int ti = a.i0;
            a.s0 = b.s0; a.i0 = b.i0;
            a.s1 = ts;   a.i1 = ti;
            if (b.s1 < a.s1 || (b.s1 == a.s1 && b.i1 < a.i1)) { a.s1 = b.s1; a.i1 = b.i1; }
        } else if (b.s0 < a.s1 || (b.s0 == a.s1 && b.i0 < a.i1)) { a.s1 = b.s0; a.i1 = b.i0; }
        const int n = bidx * 128 + t;
        idxf[n] = a.i0;
        if (a.s1 - a.s0 < TAU) {
            const int p = atomicAdd(count, 1);
            list[p] = n;
        }
    }
}

// ---------------------------------------------------------------------------
// k3: batched faithful fp32 re-score. 8 flagged rows per block, codebook
// streamed once per block, 32 independent FMA chains per thread.
// Numerics identical to the round-2/3-validated recipe.
// ---------------------------------------------------------------------------
#define RB 8
__global__ __launch_bounds__(256) void k3_refine(const float* __restrict__ z,
                                                 const float* __restrict__ emb,
                                                 const float* __restrict__ Ef,
                                                 const int* __restrict__ list,
                                                 const int* __restrict__ count,
                                                 int* __restrict__ idxf) {
    __shared__ float zsh[RB][260];       // +4 pad: breaks bank aliasing across rows
    __shared__ float zns[RB];
    __shared__ int   rows[RB];
    __shared__ float rd[256];
    __shared__ int   ri[256];
    const int t = threadIdx.x;
    const int cnt = *count;

    for (int g0 = blockIdx.x * RB; g0 < cnt; g0 += gridDim.x * RB) {
        const int nrows = min(RB, cnt - g0);
        if (t < RB) rows[t] = list[g0 + (t < nrows ? t : nrows - 1)];
        __syncthreads();
#pragma unroll
        for (int r = 0; r < RB; ++r) {
            const int row = rows[r];
            const int b = row >> 10, hw = row & 1023;
            zsh[r][t] = z[((size_t)b * C_DIM + t) * HW + hw];
        }
        __syncthreads();
        if (t < RB) {
            // numpy pairwise ||z||^2 (exact emulation)
            float blk[2];
#pragma unroll
            for (int h = 0; h < 2; ++h) {
                const float* p = &zsh[t][h * 128];
                float rr[8];
#pragma unroll
                for (int j = 0; j < 8; ++j) rr[j] = __fmul_rn(p[j], p[j]);
                for (int i = 8; i < 128; i += 8) {
#pragma unroll
                    for (int j = 0; j < 8; ++j)
                        rr[j] = __fadd_rn(rr[j], __fmul_rn(p[i + j], p[i + j]));
                }
                blk[h] = __fadd_rn(__fadd_rn(__fadd_rn(rr[0], rr[1]), __fadd_rn(rr[2], rr[3])),
                                   __fadd_rn(__fadd_rn(rr[4], rr[5]), __fadd_rn(rr[6], rr[7])));
            }
            zns[t] = __fadd_rn(blk[0], blk[1]);
        }
        __syncthreads();

        // 4 codes (t*4+q) x RB rows, sequential-FMA chains over ascending c
        float acc[4][RB];
#pragma unroll
        for (int q = 0; q < 4; ++q)
#pragma unroll
        for (int r = 0; r < RB; ++r) acc[q][r] = 0.f;

        const float* e0 = emb + (size_t)(t * 4) * C_DIM;
        for (int c = 0; c < C_DIM; c += 4) {
            float4 zv[RB];
#pragma unroll
            for (int r = 0; r < RB; ++r)
                zv[r] = *reinterpret_cast<const float4*>(&zsh[r][c]);
#pragma unroll
            for (int q = 0; q < 4; ++q) {
                const float4 ev = *reinterpret_cast<const float4*>(e0 + q * C_DIM + c);
#pragma unroll
                for (int r = 0; r < RB; ++r) {
                    float a = acc[q][r];
                    a = __fmaf_rn(zv[r].x, ev.x, a);
                    a = __fmaf_rn(zv[r].y, ev.y, a);
                    a = __fmaf_rn(zv[r].z, ev.z, a);
                    a = __fmaf_rn(zv[r].w, ev.w, a);
                    acc[q][r] = a;
                }
            }
        }

        // per-row argmin (first-wins) across the block
        for (int r = 0; r < RB; ++r) {
            const float zn = zns[r];
            float bd = 1e30f; int bidx2 = 1 << 29;
#pragma unroll
            for (int q = 0; q < 4; ++q) {
                const int code = t * 4 + q;
                const float dk = __fsub_rn(__fadd_rn(zn, Ef[code]),
                                           __fmul_rn(2.0f, acc[q][r]));
                if (dk < bd) { bd = dk; bidx2 = code; }
            }
            rd[t] = bd; ri[t] = bidx2;
            __syncthreads();
            for (int st = 128; st > 0; st >>= 1) {
                if (t < st) {
                    if (rd[t + st] < rd[t] || (rd[t + st] == rd[t] && ri[t + st] < ri[t])) {
                        rd[t] = rd[t + st]; ri[t] = ri[t + st];
                    }
                }
                __syncthreads();
            }
            if (t == 0 && r < nrows) idxf[rows[r]] = ri[0];
            __syncthreads();
        }
    }
}

// ---------------------------------------------------------------------------
// k4: zq straight-through + fp64 loss partial + indices-as-float
// ---------------------------------------------------------------------------
__global__ __launch_bounds__(256) void k4_out(const float* __restrict__ z,
                                              const float* __restrict__ emb,
                                              const int* __restrict__ idxf,
                                              float* __restrict__ out,
                                              double* __restrict__ lsum) {
    const int gid = blockIdx.x * 256 + threadIdx.x;
    if (gid < NPOS) out[(size_t)ZQ_ELEMS + 3 + gid] = (float)idxf[gid];

    const size_t stride = (size_t)gridDim.x * 256;
    double acc = 0.0;
    for (size_t v = (size_t)gid; v < (ZQ_ELEMS / 4); v += stride) {
        const size_t e = v * 4;
        const int hw = (int)(e & 1023);
        const int bc = (int)(e >> 10);
        const int c  = bc & 255;
        const int b  = bc >> 8;
        const int n  = b * 1024 + hw;
        const float4 zv = *reinterpret_cast<const float4*>(z + e);
        const int j0 = idxf[n], j1 = idxf[n + 1], j2 = idxf[n + 2], j3 = idxf[n + 3];
        const float e0 = emb[(size_t)j0 * C_DIM + c];
        const float e1 = emb[(size_t)j1 * C_DIM + c];
        const float e2 = emb[(size_t)j2 * C_DIM + c];
        const float e3 = emb[(size_t)j3 * C_DIM + c];
        float4 o;
        o.x = zv.x + (e0 - zv.x);
        o.y = zv.y + (e1 - zv.y);
        o.z = zv.z + (e2 - zv.z);
        o.w = zv.w + (e3 - zv.w);
        *reinterpret_cast<float4*>(out + e) = o;
        const double d0 = (double)e0 - (double)zv.x;
        const double d1 = (double)e1 - (double)zv.y;
        const double d2 = (double)e2 - (double)zv.z;
        const double d3 = (double)e3 - (double)zv.w;
        acc += d0 * d0 + d1 * d1 + d2 * d2 + d3 * d3;
    }
#pragma unroll
    for (int off = 32; off > 0; off >>= 1) acc += __shfl_down(acc, off);
    __shared__ double wsum[4];
    const int w = threadIdx.x >> 6, lanei = threadIdx.x & 63;
    if (lanei == 0) wsum[w] = acc;
    __syncthreads();
    if (threadIdx.x == 0) atomicAdd(lsum, wsum[0] + wsum[1] + wsum[2] + wsum[3]);
}

__global__ void k5_loss(const double* __restrict__ lsum, float* __restrict__ out) {
    const double m = *lsum / (double)ZQ_ELEMS;
    const float cm = (float)(0.25 * m);
    const float cb = (float)m;
    out[ZQ_ELEMS]     = cm + cb;
    out[ZQ_ELEMS + 1] = cm;
    out[ZQ_ELEMS + 2] = cb;
}

extern "C" void kernel_launch(void* const* d_in, const int* in_sizes, int n_in,
                              void* d_out, int out_size, void* d_ws, size_t ws_size,
                              hipStream_t stream) {
    const float* z   = (const float*)d_in[0];
    const float* emb = (const float*)d_in[1];
    float* out = (float*)d_out;
    char* ws = (char*)d_ws;

    float*  Ef    = (float*)(ws + OFF_EF);
    char*   Bb    = ws + OFF_BB;
    int*    idxf  = (int*)(ws + OFF_IDX);
    int*    list  = (int*)(ws + OFF_LIST);
    int*    count = (int*)(ws + OFF_COUNT);
    double* lsum  = (double*)(ws + OFF_LSUM);

    k1_prep<<<4, 256, 0, stream>>>(emb, Ef, Bb, count, lsum);
    k2_gemm<<<256, 512, 0, stream>>>(z, Bb, Ef, idxf, list, count);
    k3_refine<<<512, 256, 0, stream>>>(z, emb, Ef, list, count, idxf);
    k4_out<<<2048, 256, 0, stream>>>(z, emb, idxf, out, lsum);
    k5_loss<<<1, 1, 0, stream>>>(lsum, out);
}

// Round 5
// 291.584 us; speedup vs baseline: 2.1528x; 1.1036x over previous
//
#include <hip/hip_runtime.h>

// Problem constants
#define C_DIM   256
#define K_CODES 1024
#define HW      1024
#define NPOS    32768            // B*H*W
#define ZQ_ELEMS 8388608         // B*C*H*W

typedef float  f32x4  __attribute__((ext_vector_type(4)));
typedef __bf16 bf16x8 __attribute__((ext_vector_type(8)));

struct Cand { float s0, s1; int i0, i1; };

// workspace byte offsets
#define OFF_EF    0                      // 1024 f32
#define OFF_BB    4096                   // 512 KB swizzled bf16 codebook image
#define OFF_IDX   (4096 + 524288)        // 32768 int
#define OFF_LIST  (OFF_IDX + 131072)     // 32768 int
#define OFF_COUNT (OFF_LIST + 131072)    // int
#define OFF_LSUM  (OFF_COUNT + 8)        // double

#define TAU 6e-4f   // validated flag margin (rounds 3/4)

// ---------------------------------------------------------------------------
// k1: faithful fp32 ||e_k||^2 (numpy pairwise emulation, validated round 2)
//     + pack codebook to swizzled bf16 block image Bb + init count/lsum.
// ---------------------------------------------------------------------------
__global__ __launch_bounds__(256) void k1_prep(const float* __restrict__ emb,
                                               float* __restrict__ Ef,
                                               char* __restrict__ Bb,
                                               int* __restrict__ count,
                                               double* __restrict__ lsum) {
    const int k = blockIdx.x * 256 + threadIdx.x;
    if (k == 0) { *count = 0; *lsum = 0.0; }
    const float* a = emb + (size_t)k * C_DIM;

    float blk[2];
#pragma unroll
    for (int h = 0; h < 2; ++h) {
        const float* p = a + h * 128;
        float4 v0 = *reinterpret_cast<const float4*>(p);
        float4 v1 = *reinterpret_cast<const float4*>(p + 4);
        float r[8];
        r[0] = __fmul_rn(v0.x, v0.x); r[1] = __fmul_rn(v0.y, v0.y);
        r[2] = __fmul_rn(v0.z, v0.z); r[3] = __fmul_rn(v0.w, v0.w);
        r[4] = __fmul_rn(v1.x, v1.x); r[5] = __fmul_rn(v1.y, v1.y);
        r[6] = __fmul_rn(v1.z, v1.z); r[7] = __fmul_rn(v1.w, v1.w);
        for (int i = 8; i < 128; i += 8) {
            float4 w0 = *reinterpret_cast<const float4*>(p + i);
            float4 w1 = *reinterpret_cast<const float4*>(p + i + 4);
            r[0] = __fadd_rn(r[0], __fmul_rn(w0.x, w0.x));
            r[1] = __fadd_rn(r[1], __fmul_rn(w0.y, w0.y));
            r[2] = __fadd_rn(r[2], __fmul_rn(w0.z, w0.z));
            r[3] = __fadd_rn(r[3], __fmul_rn(w0.w, w0.w));
            r[4] = __fadd_rn(r[4], __fmul_rn(w1.x, w1.x));
            r[5] = __fadd_rn(r[5], __fmul_rn(w1.y, w1.y));
            r[6] = __fadd_rn(r[6], __fmul_rn(w1.z, w1.z));
            r[7] = __fadd_rn(r[7], __fmul_rn(w1.w, w1.w));
        }
        blk[h] = __fadd_rn(__fadd_rn(__fadd_rn(r[0], r[1]), __fadd_rn(r[2], r[3])),
                           __fadd_rn(__fadd_rn(r[4], r[5]), __fadd_rn(r[6], r[7])));
    }
    Ef[k] = __fadd_rn(blk[0], blk[1]);

    // --- pack Bb ---
    const int r = k & 127, tile = k >> 7;
    const int xr = ((r ^ (r >> 2)) & 3) << 4;
    char* rowbase = Bb + (size_t)(tile * 8) * 8192 + r * 64;
#pragma unroll
    for (int s = 0; s < 8; ++s) {
        const float* ep = a + s * 32;
        char* sb = rowbase + s * 8192;
#pragma unroll
        for (int g = 0; g < 4; ++g) {
            union { __bf16 h[8]; uint4 v; } pk;
#pragma unroll
            for (int j = 0; j < 8; ++j) pk.h[j] = (__bf16)ep[g * 8 + j];
            *reinterpret_cast<uint4*>(sb + ((g * 16) ^ xr)) = pk.v;
        }
    }
}

// ---------------------------------------------------------------------------
// k2: MFMA scoring GEMM (validated rounds 3/4, unchanged).
// ---------------------------------------------------------------------------
__global__ __launch_bounds__(512, 2) void k2_gemm(const float* __restrict__ z,
                                                  const char* __restrict__ Bb,
                                                  const float* __restrict__ Ef,
                                                  int* __restrict__ idxf,
                                                  int* __restrict__ list,
                                                  int* __restrict__ count) {
    __shared__ char smem[147456];          // 128KB A + 2x8KB B (Cand reuses A)
    char* As = smem;
    char* Bs = smem + 131072;

    const int t    = threadIdx.x;
    const int bidx = blockIdx.x;
    const int lane = t & 63;
    const int l15  = lane & 15, kg = lane >> 4;
    const int wid  = t >> 6;
    const int wM   = wid >> 1, wN = wid & 1;   // 4 x 2 wave grid, wave tile 32M x 64N

    const float* zt = z + (size_t)(bidx >> 3) * (C_DIM * HW) + (bidx & 7) * 128;
#pragma unroll
    for (int p = 0; p < 8; ++p) {
        const int pi  = p * 512 + t;
        const int c2  = pi >> 5;         // c-pair 0..127
        const int hwg = pi & 31;
        const float* p0 = zt + (size_t)(2 * c2) * HW + hwg * 4;
        const float4 f0 = *reinterpret_cast<const float4*>(p0);
        const float4 f1 = *reinterpret_cast<const float4*>(p0 + HW);
        const float a0v[4] = {f0.x, f0.y, f0.z, f0.w};
        const float a1v[4] = {f1.x, f1.y, f1.z, f1.w};
#pragma unroll
        for (int i = 0; i < 4; ++i) {
            const int hw = hwg * 4 + i;
            const int xr = ((hw ^ (hw >> 2)) & 7) << 4;
            const int koff = (c2 * 4) ^ xr;
            char* rowp = As + hw * 1024;
            const float x0 = a0v[i], x1 = a1v[i];
            const __bf16 h0 = (__bf16)x0, h1 = (__bf16)x1;
            const __bf16 l0 = (__bf16)(x0 - (float)h0);
            const __bf16 l1 = (__bf16)(x1 - (float)h1);
            union { __bf16 h[2]; unsigned int u; } ph, pl;
            ph.h[0] = h0; ph.h[1] = h1;
            pl.h[0] = l0; pl.h[1] = l1;
            *reinterpret_cast<unsigned int*>(rowp + koff) = ph.u;
            *reinterpret_cast<unsigned int*>(rowp + 512 + koff) = pl.u;
        }
    }
    __syncthreads();

    int arow[2], axr[2];
#pragma unroll
    for (int mi = 0; mi < 2; ++mi) {
        arow[mi] = wM * 32 + mi * 16 + l15;
        axr[mi]  = ((arow[mi] ^ (arow[mi] >> 2)) & 7) << 4;
    }
    int bcl[4], bxr[4];
#pragma unroll
    for (int ni = 0; ni < 4; ++ni) {
        bcl[ni] = wN * 64 + ni * 16 + l15;
        bxr[ni] = ((bcl[ni] ^ (bcl[ni] >> 2)) & 3) << 4;
    }

    float bs0[8], bs1[8];
    int   bi0[8], bi1[8];
#pragma unroll
    for (int s = 0; s < 8; ++s) { bs0[s] = 1e30f; bs1[s] = 1e30f; bi0[s] = 1 << 29; bi1[s] = 1 << 29; }

    const uint4* BbU = reinterpret_cast<const uint4*>(Bb);

    for (int nt = 0; nt < 8; ++nt) {
        f32x4 acc[2][4];
#pragma unroll
        for (int mi = 0; mi < 2; ++mi)
#pragma unroll
        for (int ni = 0; ni < 4; ++ni) acc[mi][ni] = f32x4{0.f, 0.f, 0.f, 0.f};

        {
            uint4 v = BbU[(size_t)(nt * 8) * 512 + t];
            *reinterpret_cast<uint4*>(Bs + t * 16) = v;
        }
        __syncthreads();

        for (int g = 0; g < 16; ++g) {
            uint4 vn;
            if (g < 15) vn = BbU[(size_t)(nt * 8 + ((g + 1) & 7)) * 512 + t];

            const char* bbuf = Bs + (g & 1) * 8192;
            bf16x8 af[2];
#pragma unroll
            for (int mi = 0; mi < 2; ++mi)
                af[mi] = *reinterpret_cast<const bf16x8*>(
                    As + arow[mi] * 1024 + ((g * 64 + kg * 16) ^ axr[mi]));
            bf16x8 bfv[4];
#pragma unroll
            for (int ni = 0; ni < 4; ++ni)
                bfv[ni] = *reinterpret_cast<const bf16x8*>(
                    bbuf + bcl[ni] * 64 + ((kg * 16) ^ bxr[ni]));
#pragma unroll
            for (int mi = 0; mi < 2; ++mi)
#pragma unroll
            for (int ni = 0; ni < 4; ++ni)
                acc[mi][ni] = __builtin_amdgcn_mfma_f32_16x16x32_bf16(af[mi], bfv[ni], acc[mi][ni], 0, 0, 0);

            if (g < 15)
                *reinterpret_cast<uint4*>(Bs + ((g + 1) & 1) * 8192 + t * 16) = vn;
            __syncthreads();
        }

#pragma unroll
        for (int ni = 0; ni < 4; ++ni) {
            const int code = nt * 128 + bcl[ni];
            const float ef = Ef[code];
#pragma unroll
            for (int mi = 0; mi < 2; ++mi) {
#pragma unroll
                for (int rr = 0; rr < 4; ++rr) {
                    const float s = ef - 2.0f * acc[mi][ni][rr];
                    const int slot = mi * 4 + rr;
                    if (s < bs0[slot] || (s == bs0[slot] && code < bi0[slot])) {
                        bs1[slot] = bs0[slot]; bi1[slot] = bi0[slot];
                        bs0[slot] = s; bi0[slot] = code;
                    } else if (s < bs1[slot] || (s == bs1[slot] && code < bi1[slot])) {
                        bs1[slot] = s; bi1[slot] = code;
                    }
                }
            }
        }
    }

#pragma unroll
    for (int slot = 0; slot < 8; ++slot) {
        float s0 = bs0[slot], s1 = bs1[slot];
        int   i0 = bi0[slot], i1 = bi1[slot];
#pragma unroll
        for (int m = 1; m <= 8; m <<= 1) {
            const float os0 = __shfl_xor(s0, m), os1 = __shfl_xor(s1, m);
            const int   oi0 = __shfl_xor(i0, m), oi1 = __shfl_xor(i1, m);
            if (os0 < s0 || (os0 == s0 && oi0 < i0)) {
                s1 = s0; i1 = i0; s0 = os0; i0 = oi0;
                if (os1 < s1 || (os1 == s1 && oi1 < i1)) { s1 = os1; i1 = oi1; }
            } else if (os0 < s1 || (os0 == s1 && oi0 < i1)) { s1 = os0; i1 = oi0; }
        }
        bs0[slot] = s0; bs1[slot] = s1; bi0[slot] = i0; bi1[slot] = i1;
    }

    Cand* cl = reinterpret_cast<Cand*>(smem);
    if (l15 == 0) {
#pragma unroll
        for (int slot = 0; slot < 8; ++slot) {
            const int mi = slot >> 2, rr = slot & 3;
            const int row = wM * 32 + mi * 16 + kg * 4 + rr;
            Cand c; c.s0 = bs0[slot]; c.s1 = bs1[slot]; c.i0 = bi0[slot]; c.i1 = bi1[slot];
            cl[row * 2 + wN] = c;
        }
    }
    __syncthreads();

    if (t < 128) {
        Cand a = cl[t * 2];
        const Cand b = cl[t * 2 + 1];
        if (b.s0 < a.s0 || (b.s0 == a.s0 && b.i0 < a.i0)) {
            const float ts = a.s0; const int ti = a.i0;
            a.s0 = b.s0; a.i0 = b.i0;
            a.s1 = ts;   a.i1 = ti;
            if (b.s1 < a.s1 || (b.s1 == a.s1 && b.i1 < a.i1)) { a.s1 = b.s1; a.i1 = b.i1; }
        } else if (b.s0 < a.s1 || (b.s0 == a.s1 && b.i0 < a.i1)) { a.s1 = b.s0; a.i1 = b.i0; }
        const int n = bidx * 128 + t;
        idxf[n] = a.i0;
        if (a.s1 - a.s0 < TAU) {
            const int p = atomicAdd(count, 1);
            list[p] = n;
        }
    }
}

// ---------------------------------------------------------------------------
// k3: LDS-tiled faithful fp32 re-score. 8 rows x 1024 codes per block.
// Codebook chunk (16 c x 1024 codes, 64KB) staged with 64B-contiguous
// per-lane global reads + issue-early/write-late. Each wave owns 256 codes
// (lane -> 4 consecutive codes); per thread 8x4 sequential-FMA chains over
// ascending c (validated numerics: fl(fl(zn+en) - fl(2*dot)), first-wins).
// ---------------------------------------------------------------------------
#define RB3 8
__global__ __launch_bounds__(256, 2) void k3_refine(const float* __restrict__ z,
                                                    const float* __restrict__ emb,
                                                    const float* __restrict__ Ef,
                                                    const int* __restrict__ list,
                                                    const int* __restrict__ count,
                                                    int* __restrict__ idxf) {
    __shared__ __align__(16) float es[16][1024];   // 64 KB chunk
    __shared__ __align__(16) float zs[256][RB3];   // 8 KB, [c][row]
    __shared__ int   rowsh[RB3];
    __shared__ float znsh[RB3];
    __shared__ float wd[4][RB3];
    __shared__ int   wi[4][RB3];

    const int t = threadIdx.x;
    const int lane = t & 63, w = t >> 6;
    const int code0 = w * 256 + lane * 4;          // this thread's 4 codes
    const int cnt = *count;

    for (int g0 = blockIdx.x * RB3; g0 < cnt; g0 += gridDim.x * RB3) {
        const int nrows = min(RB3, cnt - g0);
        if (t < RB3) rowsh[t] = list[g0 + min(t, nrows - 1)];
        __syncthreads();

        // gather z rows -> zs[c][r]
        {
            const int r = t & 7, cg = t >> 3;      // cg in [0,32): 8 c each
            const int row = rowsh[r];
            const int b = row >> 10, hw = row & 1023;
            const float* zp = z + ((size_t)b * C_DIM + cg * 8) * HW + hw;
#pragma unroll
            for (int i = 0; i < 8; ++i)
                zs[cg * 8 + i][r] = zp[(size_t)i * HW];
        }
        __syncthreads();

        if (t < RB3) {
            // numpy pairwise ||z||^2 (validated emulation)
            float blk[2];
#pragma unroll
            for (int h = 0; h < 2; ++h) {
                float rr[8];
#pragma unroll
                for (int j = 0; j < 8; ++j) {
                    const float v = zs[h * 128 + j][t];
                    rr[j] = __fmul_rn(v, v);
                }
                for (int i = 8; i < 128; i += 8) {
#pragma unroll
                    for (int j = 0; j < 8; ++j) {
                        const float v = zs[h * 128 + i + j][t];
                        rr[j] = __fadd_rn(rr[j], __fmul_rn(v, v));
                    }
                }
                blk[h] = __fadd_rn(__fadd_rn(__fadd_rn(rr[0], rr[1]), __fadd_rn(rr[2], rr[3])),
                                   __fadd_rn(__fadd_rn(rr[4], rr[5]), __fadd_rn(rr[6], rr[7])));
            }
            znsh[t] = __fadd_rn(blk[0], blk[1]);
        }

        float acc[RB3][4];
#pragma unroll
        for (int r = 0; r < RB3; ++r)
#pragma unroll
        for (int j = 0; j < 4; ++j) acc[r][j] = 0.f;

        // stage chunk 0 into regs (64B contiguous per lane)
        float4 sreg[16];
#pragma unroll
        for (int p = 0; p < 4; ++p) {
            const float* ep = emb + (size_t)(p * 256 + t) * C_DIM;
#pragma unroll
            for (int q = 0; q < 4; ++q)
                sreg[p * 4 + q] = *reinterpret_cast<const float4*>(ep + q * 4);
        }

        for (int g = 0; g < 16; ++g) {
            __syncthreads();                       // es free (prev compute done)
            // write staged chunk to es
#pragma unroll
            for (int p = 0; p < 4; ++p) {
                const int code = p * 256 + t;
#pragma unroll
                for (int q = 0; q < 4; ++q) {
                    const float4 v = sreg[p * 4 + q];
                    es[q * 4 + 0][code] = v.x;
                    es[q * 4 + 1][code] = v.y;
                    es[q * 4 + 2][code] = v.z;
                    es[q * 4 + 3][code] = v.w;
                }
            }
            // issue next chunk's loads early
            if (g < 15) {
                const int c0n = (g + 1) * 16;
#pragma unroll
                for (int p = 0; p < 4; ++p) {
                    const float* ep = emb + (size_t)(p * 256 + t) * C_DIM + c0n;
#pragma unroll
                    for (int q = 0; q < 4; ++q)
                        sreg[p * 4 + q] = *reinterpret_cast<const float4*>(ep + q * 4);
                }
            }
            __syncthreads();                       // es ready

            const int c0 = g * 16;
#pragma unroll
            for (int cc = 0; cc < 16; ++cc) {
                float zv[RB3];
                *reinterpret_cast<float4*>(&zv[0]) = *reinterpret_cast<const float4*>(&zs[c0 + cc][0]);
                *reinterpret_cast<float4*>(&zv[4]) = *reinterpret_cast<const float4*>(&zs[c0 + cc][4]);
                const float4 ev = *reinterpret_cast<const float4*>(&es[cc][code0]);
#pragma unroll
                for (int r = 0; r < RB3; ++r) {
                    acc[r][0] = __fmaf_rn(zv[r], ev.x, acc[r][0]);
                    acc[r][1] = __fmaf_rn(zv[r], ev.y, acc[r][1]);
                    acc[r][2] = __fmaf_rn(zv[r], ev.z, acc[r][2]);
                    acc[r][3] = __fmaf_rn(zv[r], ev.w, acc[r][3]);
                }
            }
        }

        // epilogue: d = fl(fl(zn+en) - fl(2*dot)), first-wins argmin
        float bd[RB3]; int bi[RB3];
#pragma unroll
        for (int r = 0; r < RB3; ++r) { bd[r] = 1e30f; bi[r] = 1 << 29; }
#pragma unroll
        for (int j = 0; j < 4; ++j) {
            const int code = code0 + j;
            const float ef = Ef[code];
#pragma unroll
            for (int r = 0; r < RB3; ++r) {
                const float dk = __fsub_rn(__fadd_rn(znsh[r], ef), __fmul_rn(2.0f, acc[r][j]));
                if (dk < bd[r]) { bd[r] = dk; bi[r] = code; }
            }
        }
        // wave-level reduce (index tiebreak == first-wins on exact ties)
#pragma unroll
        for (int m = 1; m <= 32; m <<= 1) {
#pragma unroll
            for (int r = 0; r < RB3; ++r) {
                const float od = __shfl_xor(bd[r], m);
                const int   oi = __shfl_xor(bi[r], m);
                if (od < bd[r] || (od == bd[r] && oi < bi[r])) { bd[r] = od; bi[r] = oi; }
            }
        }
        if (lane == 0) {
#pragma unroll
            for (int r = 0; r < RB3; ++r) { wd[w][r] = bd[r]; wi[w][r] = bi[r]; }
        }
        __syncthreads();
        if (t < RB3) {
            float d = wd[0][t]; int i = wi[0][t];
#pragma unroll
            for (int ww = 1; ww < 4; ++ww) {
                if (wd[ww][t] < d || (wd[ww][t] == d && wi[ww][t] < i)) { d = wd[ww][t]; i = wi[ww][t]; }
            }
            if (t < nrows) idxf[rowsh[t]] = i;
        }
        __syncthreads();
    }
}

// ---------------------------------------------------------------------------
// k4: zq straight-through + fp64 loss partial + indices-as-float
// ---------------------------------------------------------------------------
__global__ __launch_bounds__(256) void k4_out(const float* __restrict__ z,
                                              const float* __restrict__ emb,
                                              const int* __restrict__ idxf,
                                              float* __restrict__ out,
                                              double* __restrict__ lsum) {
    const int gid = blockIdx.x * 256 + threadIdx.x;
    if (gid < NPOS) out[(size_t)ZQ_ELEMS + 3 + gid] = (float)idxf[gid];

    const size_t stride = (size_t)gridDim.x * 256;
    double acc = 0.0;
    for (size_t v = (size_t)gid; v < (ZQ_ELEMS / 4); v += stride) {
        const size_t e = v * 4;
        const int hw = (int)(e & 1023);
        const int bc = (int)(e >> 10);
        const int c  = bc & 255;
        const int b  = bc >> 8;
        const int n  = b * 1024 + hw;
        const float4 zv = *reinterpret_cast<const float4*>(z + e);
        const int j0 = idxf[n], j1 = idxf[n + 1], j2 = idxf[n + 2], j3 = idxf[n + 3];
        const float e0 = emb[(size_t)j0 * C_DIM + c];
        const float e1 = emb[(size_t)j1 * C_DIM + c];
        const float e2 = emb[(size_t)j2 * C_DIM + c];
        const float e3 = emb[(size_t)j3 * C_DIM + c];
        float4 o;
        o.x = zv.x + (e0 - zv.x);
        o.y = zv.y + (e1 - zv.y);
        o.z = zv.z + (e2 - zv.z);
        o.w = zv.w + (e3 - zv.w);
        *reinterpret_cast<float4*>(out + e) = o;
        const double d0 = (double)e0 - (double)zv.x;
        const double d1 = (double)e1 - (double)zv.y;
        const double d2 = (double)e2 - (double)zv.z;
        const double d3 = (double)e3 - (double)zv.w;
        acc += d0 * d0 + d1 * d1 + d2 * d2 + d3 * d3;
    }
#pragma unroll
    for (int off = 32; off > 0; off >>= 1) acc += __shfl_down(acc, off);
    __shared__ double wsum[4];
    const int w = threadIdx.x >> 6, lanei = threadIdx.x & 63;
    if (lanei == 0) wsum[w] = acc;
    __syncthreads();
    if (threadIdx.x == 0) atomicAdd(lsum, wsum[0] + wsum[1] + wsum[2] + wsum[3]);
}

__global__ void k5_loss(const double* __restrict__ lsum, float* __restrict__ out) {
    const double m = *lsum / (double)ZQ_ELEMS;
    const float cm = (float)(0.25 * m);
    const float cb = (float)m;
    out[ZQ_ELEMS]     = cm + cb;
    out[ZQ_ELEMS + 1] = cm;
    out[ZQ_ELEMS + 2] = cb;
}

extern "C" void kernel_launch(void* const* d_in, const int* in_sizes, int n_in,
                              void* d_out, int out_size, void* d_ws, size_t ws_size,
                              hipStream_t stream) {
    const float* z   = (const float*)d_in[0];
    const float* emb = (const float*)d_in[1];
    float* out = (float*)d_out;
    char* ws = (char*)d_ws;

    float*  Ef    = (float*)(ws + OFF_EF);
    char*   Bb    = ws + OFF_BB;
    int*    idxf  = (int*)(ws + OFF_IDX);
    int*    list  = (int*)(ws + OFF_LIST);
    int*    count = (int*)(ws + OFF_COUNT);
    double* lsum  = (double*)(ws + OFF_LSUM);

    k1_prep<<<4, 256, 0, stream>>>(emb, Ef, Bb, count, lsum);
    k2_gemm<<<256, 512, 0, stream>>>(z, Bb, Ef, idxf, list, count);
    k3_refine<<<1024, 256, 0, stream>>>(z, emb, Ef, list, count, idxf);
    k4_out<<<2048, 256, 0, stream>>>(z, emb, idxf, out, lsum);
    k5_loss<<<1, 1, 0, stream>>>(lsum, out);
}

// Round 6
// 252.734 us; speedup vs baseline: 2.4838x; 1.1537x over previous
//
#include <hip/hip_runtime.h>

// Problem constants
#define C_DIM   256
#define K_CODES 1024
#define HW      1024
#define NPOS    32768            // B*H*W
#define ZQ_ELEMS 8388608         // B*C*H*W

typedef float  f32x4  __attribute__((ext_vector_type(4)));
typedef __bf16 bf16x8 __attribute__((ext_vector_type(8)));

struct Cand { float s0, s1; int i0, i1; };

// workspace byte offsets
#define OFF_EF    0                      // 1024 f32
#define OFF_BB    4096                   // 512 KB packed bf16 codebook image
#define OFF_IDX   (4096 + 524288)        // 32768 int
#define OFF_LIST  (OFF_IDX + 131072)     // 32768 int
#define OFF_COUNT (OFF_LIST + 131072)    // int
#define OFF_LSUM  (OFF_COUNT + 8)        // double

#define TAU 6e-4f   // flag margin; >=11 sigma of single-bf16 scoring error

// ---------------------------------------------------------------------------
// k1: faithful fp32 ||e_k||^2 (numpy pairwise emulation, validated round 2)
//     + pack codebook to chunk-linear swizzled bf16 image Bb + init scalars.
// Bb layout: [chunk=k>>6 (16)][substep s=c>>5 (8)][r=k&63][32 c], row=64B,
// 16B-group byte = (g*16) ^ (((r^(r>>2))&3)<<4)
// ---------------------------------------------------------------------------
__global__ __launch_bounds__(256) void k1_prep(const float* __restrict__ emb,
                                               float* __restrict__ Ef,
                                               char* __restrict__ Bb,
                                               int* __restrict__ count,
                                               double* __restrict__ lsum) {
    const int k = blockIdx.x * 256 + threadIdx.x;
    if (k == 0) { *count = 0; *lsum = 0.0; }
    const float* a = emb + (size_t)k * C_DIM;

    float blk[2];
#pragma unroll
    for (int h = 0; h < 2; ++h) {
        const float* p = a + h * 128;
        float4 v0 = *reinterpret_cast<const float4*>(p);
        float4 v1 = *reinterpret_cast<const float4*>(p + 4);
        float r[8];
        r[0] = __fmul_rn(v0.x, v0.x); r[1] = __fmul_rn(v0.y, v0.y);
        r[2] = __fmul_rn(v0.z, v0.z); r[3] = __fmul_rn(v0.w, v0.w);
        r[4] = __fmul_rn(v1.x, v1.x); r[5] = __fmul_rn(v1.y, v1.y);
        r[6] = __fmul_rn(v1.z, v1.z); r[7] = __fmul_rn(v1.w, v1.w);
        for (int i = 8; i < 128; i += 8) {
            float4 w0 = *reinterpret_cast<const float4*>(p + i);
            float4 w1 = *reinterpret_cast<const float4*>(p + i + 4);
            r[0] = __fadd_rn(r[0], __fmul_rn(w0.x, w0.x));
            r[1] = __fadd_rn(r[1], __fmul_rn(w0.y, w0.y));
            r[2] = __fadd_rn(r[2], __fmul_rn(w0.z, w0.z));
            r[3] = __fadd_rn(r[3], __fmul_rn(w0.w, w0.w));
            r[4] = __fadd_rn(r[4], __fmul_rn(w1.x, w1.x));
            r[5] = __fadd_rn(r[5], __fmul_rn(w1.y, w1.y));
            r[6] = __fadd_rn(r[6], __fmul_rn(w1.z, w1.z));
            r[7] = __fadd_rn(r[7], __fmul_rn(w1.w, w1.w));
        }
        blk[h] = __fadd_rn(__fadd_rn(__fadd_rn(r[0], r[1]), __fadd_rn(r[2], r[3])),
                           __fadd_rn(__fadd_rn(r[4], r[5]), __fadd_rn(r[6], r[7])));
    }
    Ef[k] = __fadd_rn(blk[0], blk[1]);

    // --- pack Bb (chunk-linear layout for k2 staging) ---
    const int r = k & 63, chunk = k >> 6;
    const int xr = ((r ^ (r >> 2)) & 3) << 4;
    char* base = Bb + (size_t)chunk * 32768 + r * 64;
#pragma unroll
    for (int s = 0; s < 8; ++s) {
        const float* ep = a + s * 32;
        char* sb = base + s * 4096;
#pragma unroll
        for (int g = 0; g < 4; ++g) {
            union { __bf16 h[8]; uint4 v; } pk;
#pragma unroll
            for (int j = 0; j < 8; ++j) pk.h[j] = (__bf16)ep[g * 8 + j];
            *reinterpret_cast<uint4*>(sb + ((g * 16) ^ xr)) = pk.v;
        }
    }
}

// ---------------------------------------------------------------------------
// k2: MFMA scoring GEMM, chunked pipeline.
//  - A resident: 128 pos x 256 c bf16 (64 KB), XOR-swizzled; frags hoisted
//    into 64 VGPRs once.
//  - B: 16 chunks of 64 codes x 256 c (32 KB), double-buffered, reg-staged
//    issue-early/write-late; ONE barrier per chunk.
//  - per chunk per wave: 16 ds_read_b128 + 32 MFMA; epilogue folds top-2.
// ---------------------------------------------------------------------------
__global__ __launch_bounds__(512, 2) void k2_gemm(const float* __restrict__ z,
                                                  const char* __restrict__ Bb,
                                                  const float* __restrict__ Ef,
                                                  int* __restrict__ idxf,
                                                  int* __restrict__ list,
                                                  int* __restrict__ count) {
    __shared__ char smem[131072];          // 64KB A + 2x32KB B (Cand reuses A)
    char* As = smem;
    char* Bs = smem + 65536;

    const int t    = threadIdx.x;
    const int bidx = blockIdx.x;
    const int lane = t & 63;
    const int l15  = lane & 15, kg = lane >> 4;
    const int wid  = t >> 6;
    const int wM   = wid >> 1, wN = wid & 1;   // 4M x 2N waves; wave tile 32x32

    // ---- prologue: issue chunk-0 stage loads (fly during A-fill) ----
    uint4 stg[4];
#pragma unroll
    for (int i = 0; i < 4; ++i)
        stg[i] = *reinterpret_cast<const uint4*>(Bb + i * 8192 + t * 16);

    // ---- A fill: transpose z tile -> As[hw][c] bf16, row 512B, swizzled ----
    const float* zt = z + (size_t)(bidx >> 3) * (C_DIM * HW) + (bidx & 7) * 128;
#pragma unroll
    for (int p = 0; p < 8; ++p) {
        const int pi  = p * 512 + t;
        const int c2  = pi >> 5;         // c-pair 0..127
        const int hwg = pi & 31;
        const float* p0 = zt + (size_t)(2 * c2) * HW + hwg * 4;
        const float4 f0 = *reinterpret_cast<const float4*>(p0);
        const float4 f1 = *reinterpret_cast<const float4*>(p0 + HW);
        const float a0v[4] = {f0.x, f0.y, f0.z, f0.w};
        const float a1v[4] = {f1.x, f1.y, f1.z, f1.w};
#pragma unroll
        for (int i = 0; i < 4; ++i) {
            const int hw = hwg * 4 + i;
            const int xr = ((hw ^ (hw >> 2)) & 7) << 4;
            const int koff = (c2 * 4) ^ xr;
            union { __bf16 h[2]; unsigned int u; } ph;
            ph.h[0] = (__bf16)a0v[i];
            ph.h[1] = (__bf16)a1v[i];
            *reinterpret_cast<unsigned int*>(As + hw * 512 + koff) = ph.u;
        }
    }
    // write chunk-0 stage into buf0 (lane-contiguous 16B: conflict-free)
#pragma unroll
    for (int i = 0; i < 4; ++i)
        *reinterpret_cast<uint4*>(Bs + i * 8192 + t * 16) = stg[i];
    __syncthreads();

    // ---- hoist A fragments (validated layout; one-time) ----
    bf16x8 af[2][8];
#pragma unroll
    for (int mi = 0; mi < 2; ++mi) {
        const int row = wM * 32 + mi * 16 + l15;
        const int axr = ((row ^ (row >> 2)) & 7) << 4;
#pragma unroll
        for (int ks = 0; ks < 8; ++ks)
            af[mi][ks] = *reinterpret_cast<const bf16x8*>(
                As + row * 512 + ((ks * 64 + kg * 16) ^ axr));
    }

    int brow[2], bxr[2];
#pragma unroll
    for (int ni = 0; ni < 2; ++ni) {
        brow[ni] = wN * 32 + ni * 16 + l15;
        bxr[ni]  = ((brow[ni] ^ (brow[ni] >> 2)) & 3) << 4;
    }

    float bs0[8], bs1[8];
    int   bi0[8], bi1[8];
#pragma unroll
    for (int s = 0; s < 8; ++s) { bs0[s] = 1e30f; bs1[s] = 1e30f; bi0[s] = 1 << 29; bi1[s] = 1 << 29; }

    // ---- main chunk loop: 16 chunks of 64 codes, 1 barrier each ----
    for (int g = 0; g < 16; ++g) {
        if (g < 15) {   // issue next-chunk loads early (hidden under compute)
#pragma unroll
            for (int i = 0; i < 4; ++i)
                stg[i] = *reinterpret_cast<const uint4*>(
                    Bb + (size_t)(g + 1) * 32768 + i * 8192 + t * 16);
        }
        const char* bbuf = Bs + (g & 1) * 32768;
        f32x4 acc[2][2];
#pragma unroll
        for (int mi = 0; mi < 2; ++mi)
#pragma unroll
        for (int ni = 0; ni < 2; ++ni) acc[mi][ni] = f32x4{0.f, 0.f, 0.f, 0.f};

#pragma unroll
        for (int ks = 0; ks < 8; ++ks) {
            bf16x8 bf[2];
#pragma unroll
            for (int ni = 0; ni < 2; ++ni)
                bf[ni] = *reinterpret_cast<const bf16x8*>(
                    bbuf + ks * 4096 + brow[ni] * 64 + ((kg * 16) ^ bxr[ni]));
#pragma unroll
            for (int mi = 0; mi < 2; ++mi)
#pragma unroll
            for (int ni = 0; ni < 2; ++ni)
                acc[mi][ni] = __builtin_amdgcn_mfma_f32_16x16x32_bf16(
                    af[mi][ks], bf[ni], acc[mi][ni], 0, 0, 0);
        }

        if (g < 15) {   // write-late into the other buffer
            char* nbuf = Bs + ((g + 1) & 1) * 32768;
#pragma unroll
            for (int i = 0; i < 4; ++i)
                *reinterpret_cast<uint4*>(nbuf + i * 8192 + t * 16) = stg[i];
        }

        // epilogue: fold scores into per-lane top-2 (codes ascending)
#pragma unroll
        for (int ni = 0; ni < 2; ++ni) {
            const int code = g * 64 + brow[ni];
            const float ef = Ef[code];
#pragma unroll
            for (int mi = 0; mi < 2; ++mi) {
#pragma unroll
                for (int rr = 0; rr < 4; ++rr) {
                    const float s = ef - 2.0f * acc[mi][ni][rr];
                    const int slot = mi * 4 + rr;
                    if (s < bs0[slot] || (s == bs0[slot] && code < bi0[slot])) {
                        bs1[slot] = bs0[slot]; bi1[slot] = bi0[slot];
                        bs0[slot] = s; bi0[slot] = code;
                    } else if (s < bs1[slot] || (s == bs1[slot] && code < bi1[slot])) {
                        bs1[slot] = s; bi1[slot] = code;
                    }
                }
            }
        }
        __syncthreads();
    }

    // cross-lane top-2 merge over the 16 column-lanes
#pragma unroll
    for (int slot = 0; slot < 8; ++slot) {
        float s0 = bs0[slot], s1 = bs1[slot];
        int   i0 = bi0[slot], i1 = bi1[slot];
#pragma unroll
        for (int m = 1; m <= 8; m <<= 1) {
            const float os0 = __shfl_xor(s0, m), os1 = __shfl_xor(s1, m);
            const int   oi0 = __shfl_xor(i0, m), oi1 = __shfl_xor(i1, m);
            if (os0 < s0 || (os0 == s0 && oi0 < i0)) {
                s1 = s0; i1 = i0; s0 = os0; i0 = oi0;
                if (os1 < s1 || (os1 == s1 && oi1 < i1)) { s1 = os1; i1 = oi1; }
            } else if (os0 < s1 || (os0 == s1 && oi0 < i1)) { s1 = os0; i1 = oi0; }
        }
        bs0[slot] = s0; bs1[slot] = s1; bi0[slot] = i0; bi1[slot] = i1;
    }

    // A-region is dead now; reuse as Cand[128][2]
    Cand* cl = reinterpret_cast<Cand*>(smem);
    if (l15 == 0) {
#pragma unroll
        for (int slot = 0; slot < 8; ++slot) {
            const int mi = slot >> 2, rr = slot & 3;
            const int row = wM * 32 + mi * 16 + kg * 4 + rr;
            Cand c; c.s0 = bs0[slot]; c.s1 = bs1[slot]; c.i0 = bi0[slot]; c.i1 = bi1[slot];
            cl[row * 2 + wN] = c;
        }
    }
    __syncthreads();

    if (t < 128) {
        Cand a = cl[t * 2];
        const Cand b = cl[t * 2 + 1];
        if (b.s0 < a.s0 || (b.s0 == a.s0 && b.i0 < a.i0)) {
            const float ts = a.s0; const int ti = a.i0;
            a.s0 = b.s0; a.i0 = b.i0;
            a.s1 = ts;   a.i1 = ti;
            if (b.s1 < a.s1 || (b.s1 == a.s1 && b.i1 < a.i1)) { a.s1 = b.s1; a.i1 = b.i1; }
        } else if (b.s0 < a.s1 || (b.s0 == a.s1 && b.i0 < a.i1)) { a.s1 = b.s0; a.i1 = b.i0; }
        const int n = bidx * 128 + t;
        idxf[n] = a.i0;
        if (a.s1 - a.s0 < TAU) {
            const int p = atomicAdd(count, 1);
            list[p] = n;
        }
    }
}

// ---------------------------------------------------------------------------
// k3: LDS-tiled faithful fp32 re-score (validated round 5, unchanged).
// ---------------------------------------------------------------------------
#define RB3 8
__global__ __launch_bounds__(256, 2) void k3_refine(const float* __restrict__ z,
                                                    const float* __restrict__ emb,
                                                    const float* __restrict__ Ef,
                                                    const int* __restrict__ list,
                                                    const int* __restrict__ count,
                                                    int* __restrict__ idxf) {
    __shared__ __align__(16) float es[16][1024];   // 64 KB chunk
    __shared__ __align__(16) float zs[256][RB3];   // 8 KB, [c][row]
    __shared__ int   rowsh[RB3];
    __shared__ float znsh[RB3];
    __shared__ float wd[4][RB3];
    __shared__ int   wi[4][RB3];

    const int t = threadIdx.x;
    const int lane = t & 63, w = t >> 6;
    const int code0 = w * 256 + lane * 4;          // this thread's 4 codes
    const int cnt = *count;

    for (int g0 = blockIdx.x * RB3; g0 < cnt; g0 += gridDim.x * RB3) {
        const int nrows = min(RB3, cnt - g0);
        if (t < RB3) rowsh[t] = list[g0 + min(t, nrows - 1)];
        __syncthreads();

        {
            const int r = t & 7, cg = t >> 3;
            const int row = rowsh[r];
            const int b = row >> 10, hw = row & 1023;
            const float* zp = z + ((size_t)b * C_DIM + cg * 8) * HW + hw;
#pragma unroll
            for (int i = 0; i < 8; ++i)
                zs[cg * 8 + i][r] = zp[(size_t)i * HW];
        }
        __syncthreads();

        if (t < RB3) {
            float blk[2];
#pragma unroll
            for (int h = 0; h < 2; ++h) {
                float rr[8];
#pragma unroll
                for (int j = 0; j < 8; ++j) {
                    const float v = zs[h * 128 + j][t];
                    rr[j] = __fmul_rn(v, v);
                }
                for (int i = 8; i < 128; i += 8) {
#pragma unroll
                    for (int j = 0; j < 8; ++j) {
                        const float v = zs[h * 128 + i + j][t];
                        rr[j] = __fadd_rn(rr[j], __fmul_rn(v, v));
                    }
                }
                blk[h] = __fadd_rn(__fadd_rn(__fadd_rn(rr[0], rr[1]), __fadd_rn(rr[2], rr[3])),
                                   __fadd_rn(__fadd_rn(rr[4], rr[5]), __fadd_rn(rr[6], rr[7])));
            }
            znsh[t] = __fadd_rn(blk[0], blk[1]);
        }

        float acc[RB3][4];
#pragma unroll
        for (int r = 0; r < RB3; ++r)
#pragma unroll
        for (int j = 0; j < 4; ++j) acc[r][j] = 0.f;

        float4 sreg[16];
#pragma unroll
        for (int p = 0; p < 4; ++p) {
            const float* ep = emb + (size_t)(p * 256 + t) * C_DIM;
#pragma unroll
            for (int q = 0; q < 4; ++q)
                sreg[p * 4 + q] = *reinterpret_cast<const float4*>(ep + q * 4);
        }

        for (int g = 0; g < 16; ++g) {
            __syncthreads();
#pragma unroll
            for (int p = 0; p < 4; ++p) {
                const int code = p * 256 + t;
#pragma unroll
                for (int q = 0; q < 4; ++q) {
                    const float4 v = sreg[p * 4 + q];
                    es[q * 4 + 0][code] = v.x;
                    es[q * 4 + 1][code] = v.y;
                    es[q * 4 + 2][code] = v.z;
                    es[q * 4 + 3][code] = v.w;
                }
            }
            if (g < 15) {
                const int c0n = (g + 1) * 16;
#pragma unroll
                for (int p = 0; p < 4; ++p) {
                    const float* ep = emb + (size_t)(p * 256 + t) * C_DIM + c0n;
#pragma unroll
                    for (int q = 0; q < 4; ++q)
                        sreg[p * 4 + q] = *reinterpret_cast<const float4*>(ep + q * 4);
                }
            }
            __syncthreads();

            const int c0 = g * 16;
#pragma unroll
            for (int cc = 0; cc < 16; ++cc) {
                float zv[RB3];
                *reinterpret_cast<float4*>(&zv[0]) = *reinterpret_cast<const float4*>(&zs[c0 + cc][0]);
                *reinterpret_cast<float4*>(&zv[4]) = *reinterpret_cast<const float4*>(&zs[c0 + cc][4]);
                const float4 ev = *reinterpret_cast<const float4*>(&es[cc][code0]);
#pragma unroll
                for (int r = 0; r < RB3; ++r) {
                    acc[r][0] = __fmaf_rn(zv[r], ev.x, acc[r][0]);
                    acc[r][1] = __fmaf_rn(zv[r], ev.y, acc[r][1]);
                    acc[r][2] = __fmaf_rn(zv[r], ev.z, acc[r][2]);
                    acc[r][3] = __fmaf_rn(zv[r], ev.w, acc[r][3]);
                }
            }
        }

        float bd[RB3]; int bi[RB3];
#pragma unroll
        for (int r = 0; r < RB3; ++r) { bd[r] = 1e30f; bi[r] = 1 << 29; }
#pragma unroll
        for (int j = 0; j < 4; ++j) {
            const int code = code0 + j;
            const float ef = Ef[code];
#pragma unroll
            for (int r = 0; r < RB3; ++r) {
                const float dk = __fsub_rn(__fadd_rn(znsh[r], ef), __fmul_rn(2.0f, acc[r][j]));
                if (dk < bd[r]) { bd[r] = dk; bi[r] = code; }
            }
        }
#pragma unroll
        for (int m = 1; m <= 32; m <<= 1) {
#pragma unroll
            for (int r = 0; r < RB3; ++r) {
                const float od = __shfl_xor(bd[r], m);
                const int   oi = __shfl_xor(bi[r], m);
                if (od < bd[r] || (od == bd[r] && oi < bi[r])) { bd[r] = od; bi[r] = oi; }
            }
        }
        if (lane == 0) {
#pragma unroll
            for (int r = 0; r < RB3; ++r) { wd[w][r] = bd[r]; wi[w][r] = bi[r]; }
        }
        __syncthreads();
        if (t < RB3) {
            float d = wd[0][t]; int i = wi[0][t];
#pragma unroll
            for (int ww = 1; ww < 4; ++ww) {
                if (wd[ww][t] < d || (wd[ww][t] == d && wi[ww][t] < i)) { d = wd[ww][t]; i = wi[ww][t]; }
            }
            if (t < nrows) idxf[rowsh[t]] = i;
        }
        __syncthreads();
    }
}

// ---------------------------------------------------------------------------
// k4: zq straight-through + fp64 loss partial + indices-as-float
// ---------------------------------------------------------------------------
__global__ __launch_bounds__(256) void k4_out(const float* __restrict__ z,
                                              const float* __restrict__ emb,
                                              const int* __restrict__ idxf,
                                              float* __restrict__ out,
                                              double* __restrict__ lsum) {
    const int gid = blockIdx.x * 256 + threadIdx.x;
    if (gid < NPOS) out[(size_t)ZQ_ELEMS + 3 + gid] = (float)idxf[gid];

    const size_t stride = (size_t)gridDim.x * 256;
    double acc = 0.0;
    for (size_t v = (size_t)gid; v < (ZQ_ELEMS / 4); v += stride) {
        const size_t e = v * 4;
        const int hw = (int)(e & 1023);
        const int bc = (int)(e >> 10);
        const int c  = bc & 255;
        const int b  = bc >> 8;
        const int n  = b * 1024 + hw;
        const float4 zv = *reinterpret_cast<const float4*>(z + e);
        const int j0 = idxf[n], j1 = idxf[n + 1], j2 = idxf[n + 2], j3 = idxf[n + 3];
        const float e0 = emb[(size_t)j0 * C_DIM + c];
        const float e1 = emb[(size_t)j1 * C_DIM + c];
        const float e2 = emb[(size_t)j2 * C_DIM + c];
        const float e3 = emb[(size_t)j3 * C_DIM + c];
        float4 o;
        o.x = zv.x + (e0 - zv.x);
        o.y = zv.y + (e1 - zv.y);
        o.z = zv.z + (e2 - zv.z);
        o.w = zv.w + (e3 - zv.w);
        *reinterpret_cast<float4*>(out + e) = o;
        const double d0 = (double)e0 - (double)zv.x;
        const double d1 = (double)e1 - (double)zv.y;
        const double d2 = (double)e2 - (double)zv.z;
        const double d3 = (double)e3 - (double)zv.w;
        acc += d0 * d0 + d1 * d1 + d2 * d2 + d3 * d3;
    }
#pragma unroll
    for (int off = 32; off > 0; off >>= 1) acc += __shfl_down(acc, off);
    __shared__ double wsum[4];
    const int w = threadIdx.x >> 6, lanei = threadIdx.x & 63;
    if (lanei == 0) wsum[w] = acc;
    __syncthreads();
    if (threadIdx.x == 0) atomicAdd(lsum, wsum[0] + wsum[1] + wsum[2] + wsum[3]);
}

__global__ void k5_loss(const double* __restrict__ lsum, float* __restrict__ out) {
    const double m = *lsum / (double)ZQ_ELEMS;
    const float cm = (float)(0.25 * m);
    const float cb = (float)m;
    out[ZQ_ELEMS]     = cm + cb;
    out[ZQ_ELEMS + 1] = cm;
    out[ZQ_ELEMS + 2] = cb;
}

extern "C" void kernel_launch(void* const* d_in, const int* in_sizes, int n_in,
                              void* d_out, int out_size, void* d_ws, size_t ws_size,
                              hipStream_t stream) {
    const float* z   = (const float*)d_in[0];
    const float* emb = (const float*)d_in[1];
    float* out = (float*)d_out;
    char* ws = (char*)d_ws;

    float*  Ef    = (float*)(ws + OFF_EF);
    char*   Bb    = ws + OFF_BB;
    int*    idxf  = (int*)(ws + OFF_IDX);
    int*    list  = (int*)(ws + OFF_LIST);
    int*    count = (int*)(ws + OFF_COUNT);
    double* lsum  = (double*)(ws + OFF_LSUM);

    k1_prep<<<4, 256, 0, stream>>>(emb, Ef, Bb, count, lsum);
    k2_gemm<<<256, 512, 0, stream>>>(z, Bb, Ef, idxf, list, count);
    k3_refine<<<1024, 256, 0, stream>>>(z, emb, Ef, list, count, idxf);
    k4_out<<<2048, 256, 0, stream>>>(z, emb, idxf, out, lsum);
    k5_loss<<<1, 1, 0, stream>>>(lsum, out);
}